// Round 7
// baseline (327.841 us; speedup 1.0000x reference)
//
#include <hip/hip_runtime.h>

typedef __attribute__((ext_vector_type(8))) short short8;
typedef __attribute__((ext_vector_type(4))) float f32x4;
typedef __attribute__((ext_vector_type(2))) unsigned int u32x2;
typedef unsigned short u16;

static constexpr int BATCH = 8;
static constexpr int NDIM  = 2048;
static constexpr int MDIM  = 2048;
static constexpr int EDIM  = 1024;
static constexpr int BM    = 128;
static constexpr int BN    = 128;
static constexpr int BK    = 64;

#define BAR() do { asm volatile("" ::: "memory"); \
                   __builtin_amdgcn_s_barrier(); \
                   asm volatile("" ::: "memory"); } while (0)
#define WFENCE() asm volatile("s_waitcnt lgkmcnt(0)" ::: "memory")

// Fused fp32->bf16 128x128 GEMM, 4 waves, 2 blocks/CU, ONE barrier per K-tile.
// R6 post-mortem: 2 barriers/tile + WRT-after-MFMA exposed global-load latency
// and serialized phases (3150 cyc/phase for 540 cyc of MFMA). Within a tile,
// every wave reads only buf b and ds_writes only buf w, so the mid-tile
// barrier protected nothing. R7 tile schedule:
//   ds_reads(ar01, br, ar23) -> MM half0 -> WRT tile u+1 (vmcnt wait hidden
//   under MFMA) -> ISS tile u+2 -> MM half1 -> WFENCE -> BAR
// 16 barriers/block total. Tail guarded (R6's clamp re-fetched 2 dead tiles,
// +150 MB FETCH).
__global__ __launch_bounds__(256, 2)
void bmm_fused_kernel(const float* __restrict__ A, const float* __restrict__ B,
                      float* __restrict__ C) {
  __shared__ u16 sh[2][2][BM * BK];   // [buf][A=0/B=1][128 x 64] = 64 KiB

  const int tid  = threadIdx.x;
  const int lane = tid & 63;
  const int wave = tid >> 6;      // 0..3
  const int quad = lane >> 4;
  const int ml   = lane & 15;
  const int wrow = (wave >> 1) * 64;
  const int wcol = (wave & 1) * 64;

  // XCD-bijective swizzle: 2048 blocks = 8 XCDs x 256; XCD x owns batch x.
  const int flat  = (int)blockIdx.x + 16 * (int)blockIdx.y + 256 * (int)blockIdx.z;
  const int nf    = (flat & 7) * 256 + (flat >> 3);
  const int batch = nf >> 8;
  const int trow  = (nf >> 4) & 15;
  const int tcol  = nf & 15;

  const float* Ab = A + (size_t)batch * NDIM * EDIM + (size_t)trow * BM * EDIM;
  const float* Bb = B + (size_t)batch * MDIM * EDIM + (size_t)tcol * BN * EDIM;

  // ---- staging addressing (R4-R6 verified) ----
  // unit = 64 rows x 64 cols. Thread: rows rowb + j*16 (j=0..3), fp32 cols
  // colf..colf+3 -> 2 cvt_pk -> one ds_write_b64. Swizzle: 16B chunk c of
  // row r stored at chunk c ^ (r&7); r&7 == rowb&7.
  const int rowb = tid >> 4;                  // 0..15
  const int ci   = tid & 15;
  const int colf = ci * 4;
  const int swzoff = (((ci >> 1) ^ (rowb & 7)) << 3) | ((ci & 1) << 2);
  const float* pA = Ab + (size_t)rowb * EDIM + colf;
  const float* pB = Bb + (size_t)rowb * EDIM + colf;

  // ---- ds_read fragment addressing (swizzled; R1/R4-R6 verified) ----
  const int aOff = (wrow + ml) * 64;
  const int bOff = (wcol + ml) * 64;
  const int kc0 = ((quad    ) ^ (ml & 7)) * 8;
  const int kc1 = ((quad + 4) ^ (ml & 7)) * 8;

  short8 ar[4][2], br[4][2];
  f32x4 acc[4][4] = {};
  f32x4 SA0[4], SA1[4], SB0[4], SB1[4];   // 4 staging sets

#define ISS(Sp, P, u, t) do {                                                  \
    const float* _p = (P) + (size_t)((u) * 64) * EDIM + (size_t)(t) * BK;      \
    Sp[0] = *(const f32x4*)(_p);                                               \
    Sp[1] = *(const f32x4*)(_p + (size_t)16 * EDIM);                           \
    Sp[2] = *(const f32x4*)(_p + (size_t)32 * EDIM);                           \
    Sp[3] = *(const f32x4*)(_p + (size_t)48 * EDIM);                           \
  } while (0)

#define WRT(Sp, buf, ab, u) do {                                               \
    _Pragma("unroll")                                                          \
    for (int _j = 0; _j < 4; ++_j) {                                           \
      unsigned _lo, _hi;                                                       \
      asm("v_cvt_pk_bf16_f32 %0, %1, %2"                                       \
          : "=v"(_lo) : "v"(Sp[_j][0]), "v"(Sp[_j][1]));                       \
      asm("v_cvt_pk_bf16_f32 %0, %1, %2"                                       \
          : "=v"(_hi) : "v"(Sp[_j][2]), "v"(Sp[_j][3]));                       \
      u32x2 _u; _u[0] = _lo; _u[1] = _hi;                                      \
      *(u32x2*)&sh[buf][ab][((u) * 64 + rowb + _j * 16) * 64 + swzoff] = _u;   \
    } } while (0)

  // A sub-rows s (wrow + s*16): s=0..1 then s=2..3 issued separately so the
  // first MFMA half's operands complete earliest.
#define LDA01(buf) do {                                                        \
    _Pragma("unroll")                                                          \
    for (int _s = 0; _s < 2; ++_s) {                                           \
      ar[_s][0] = *(const short8*)&sh[buf][0][aOff + _s*1024 + kc0];           \
      ar[_s][1] = *(const short8*)&sh[buf][0][aOff + _s*1024 + kc1];           \
    } } while (0)

#define LDA23(buf) do {                                                        \
    _Pragma("unroll")                                                          \
    for (int _s = 2; _s < 4; ++_s) {                                           \
      ar[_s][0] = *(const short8*)&sh[buf][0][aOff + _s*1024 + kc0];           \
      ar[_s][1] = *(const short8*)&sh[buf][0][aOff + _s*1024 + kc1];           \
    } } while (0)

#define LDBALL(buf) do {                                                       \
    _Pragma("unroll")                                                          \
    for (int _n = 0; _n < 4; ++_n) {                                           \
      br[_n][0] = *(const short8*)&sh[buf][1][bOff + _n*1024 + kc0];           \
      br[_n][1] = *(const short8*)&sh[buf][1][bOff + _n*1024 + kc1];           \
    } } while (0)

  // 16 MFMA: A sub-rows {h*2, h*2+1} x all 64 B-cols x K=64
#define MMH(h) do {                                                            \
    __builtin_amdgcn_s_setprio(1);                                             \
    _Pragma("unroll")                                                          \
    for (int _sa = (h)*2; _sa < (h)*2 + 2; ++_sa)                              \
      _Pragma("unroll")                                                        \
      for (int _n = 0; _n < 4; ++_n)                                           \
        _Pragma("unroll")                                                      \
        for (int _ks = 0; _ks < 2; ++_ks)                                      \
          acc[_sa][_n] = __builtin_amdgcn_mfma_f32_16x16x32_bf16(              \
              ar[_sa][_ks], br[_n][_ks], acc[_sa][_n], 0, 0, 0);               \
    __builtin_amdgcn_s_setprio(0);                                             \
  } while (0)

  // ---- prologue: buf0 <- tile0 (direct); sets <- tile1 (pending) ----
  ISS(SA0, pA, 0, 0); ISS(SA1, pA, 1, 0); ISS(SB0, pB, 0, 0); ISS(SB1, pB, 1, 0);
  WRT(SA0, 0, 0, 0);  WRT(SA1, 0, 0, 1);  WRT(SB0, 0, 1, 0);  WRT(SB1, 0, 1, 1);
  ISS(SA0, pA, 0, 1); ISS(SA1, pA, 1, 1); ISS(SB0, pB, 0, 1); ISS(SB1, pB, 1, 1);
  WFENCE();
  BAR();

  // ---- main loop: tile u read from buf u&1; writes tile u+1 -> buf (u+1)&1;
  //      ISS tile u+2. One fence+barrier per tile. ----
#pragma unroll 1
  for (int u = 0; u < 16; ++u) {
    const int b = u & 1;
    const int w = b ^ 1;
    // 16 ds_reads, first-half operands first
    LDA01(b); LDBALL(b); LDA23(b);
    // half 0: 16 MFMA (overlaps the vmcnt wait of the WRTs below)
    MMH(0);
    // stage tile u+1 into buf w (consumes sets ISS'd at tile u-1)
    if (u < 15) {
      WRT(SA0, w, 0, 0); WRT(SA1, w, 0, 1);
      WRT(SB0, w, 1, 0); WRT(SB1, w, 1, 1);
    }
    // issue tile u+2
    if (u < 14) {
      ISS(SA0, pA, 0, u + 2); ISS(SA1, pA, 1, u + 2);
      ISS(SB0, pB, 0, u + 2); ISS(SB1, pB, 1, u + 2);
    }
    // half 1: 16 MFMA
    MMH(1);
    WFENCE(); BAR();
  }

  // ---- C write (verified mapping: row = quad*4 + r, col = ml) ----
  float* Cb = C + (size_t)batch * NDIM * MDIM
                + (size_t)(trow * BM + wrow + quad * 4) * MDIM
                + (tcol * BN + wcol + ml);
#pragma unroll
  for (int mi = 0; mi < 4; ++mi) {
#pragma unroll
    for (int ni = 0; ni < 4; ++ni) {
      float* cp = Cb + (size_t)(mi * 16) * MDIM + ni * 16;
#pragma unroll
      for (int r = 0; r < 4; ++r)
        cp[(size_t)r * MDIM] = acc[mi][ni][r];
    }
  }
#undef ISS
#undef WRT
#undef LDA01
#undef LDA23
#undef LDBALL
#undef MMH
}

extern "C" void kernel_launch(void* const* d_in, const int* in_sizes, int n_in,
                              void* d_out, int out_size, void* d_ws, size_t ws_size,
                              hipStream_t stream) {
  const float* A = (const float*)d_in[0];
  const float* B = (const float*)d_in[1];
  float*       C = (float*)d_out;
  (void)d_ws; (void)ws_size;

  dim3 grid(MDIM / BN, NDIM / BM, BATCH);   // 16 x 16 x 8 = 2048
  bmm_fused_kernel<<<grid, dim3(256), 0, stream>>>(A, B, C);
}

// Round 8
// 296.218 us; speedup vs baseline: 1.1068x; 1.1068x over previous
//
#include <hip/hip_runtime.h>
#include <hip/hip_bf16.h>

typedef __attribute__((ext_vector_type(8))) short short8;
typedef __attribute__((ext_vector_type(4))) float f32x4;
typedef __attribute__((ext_vector_type(4))) unsigned int u32x4;
typedef unsigned short u16;
typedef __attribute__((address_space(1))) void gvoid;
typedef __attribute__((address_space(3))) void lvoid;

static constexpr int BATCH = 8;
static constexpr int NDIM  = 2048;
static constexpr int MDIM  = 2048;
static constexpr int EDIM  = 1024;

// ---------------- phase 1: fp32 -> bf16 (RNE), grid-stride ----------------
// R8: old version used 16384 single-shot blocks (1 load->store round trip per
// thread) and ran at ~3.2 TB/s. Grid-stride over 2048 blocks with A and B
// processed per iteration (64B loads + 32B stores per thread-iter, 4 iters)
// gives deep MLP -> target ~5 TB/s on the 201 MB stream.
__device__ __forceinline__ unsigned bf16rne_pair(float a, float b) {
  unsigned ua = __float_as_uint(a), ub = __float_as_uint(b);
  ua = (ua + 0x7FFFu + ((ua >> 16) & 1u)) >> 16;
  ub = (ub + 0x7FFFu + ((ub >> 16) & 1u)) >> 16;
  return ua | (ub << 16);
}

__device__ __forceinline__ u32x4 cvt8(f32x4 x, f32x4 y) {
  u32x4 r;
  r[0] = bf16rne_pair(x[0], x[1]);
  r[1] = bf16rne_pair(x[2], x[3]);
  r[2] = bf16rne_pair(y[0], y[1]);
  r[3] = bf16rne_pair(y[2], y[3]);
  return r;
}

__global__ __launch_bounds__(256)
void cvt_kernel(const float* __restrict__ A, const float* __restrict__ B,
                u16* __restrict__ Abf, u16* __restrict__ Bbf) {
  const size_t elems  = (size_t)BATCH * NDIM * EDIM;          // 16.78M / matrix
  const size_t stride = (size_t)gridDim.x * blockDim.x * 8;
  for (size_t idx = ((size_t)blockIdx.x * blockDim.x + threadIdx.x) * 8;
       idx < elems; idx += stride) {
    f32x4 xa = *(const f32x4*)(A + idx);
    f32x4 ya = *(const f32x4*)(A + idx + 4);
    f32x4 xb = *(const f32x4*)(B + idx);
    f32x4 yb = *(const f32x4*)(B + idx + 4);
    *(u32x4*)(Abf + idx) = cvt8(xa, ya);
    *(u32x4*)(Bbf + idx) = cvt8(xb, yb);
  }
}

// ---------------- phase 2: 256x256 8-phase bf16 GEMM (R1-verified) ----------------
__device__ __forceinline__ void async_cp16(const void* g, void* l) {
  __builtin_amdgcn_global_load_lds((gvoid*)g, (lvoid*)l, 16, 0, 0);
}

#define BAR() do { asm volatile("" ::: "memory"); \
                   __builtin_amdgcn_s_barrier(); \
                   asm volatile("" ::: "memory"); } while (0)
#define WAITVM(N) asm volatile("s_waitcnt vmcnt(" #N ")" ::: "memory")

static constexpr int BM = 256;
static constexpr int BN = 256;
static constexpr int BK = 64;

__global__ __launch_bounds__(512, 2)
void bmm_8ph_kernel(const u16* __restrict__ A, const u16* __restrict__ B,
                    float* __restrict__ C) {
  // [buf][A=0/B=1][256 rows x 64 cols], XOR-swizzled at 16B-chunk granularity:
  // LDS[r][chunk c] holds global chunk (r, c ^ (r&7)).  128 KiB total.
  __shared__ u16 sh[2][2][BM * BK];

  const int tid  = threadIdx.x;
  const int lane = tid & 63;
  const int wave = tid >> 6;      // 0..7
  const int wr   = wave >> 2;     // 0..1  (wave-row: 128-row slab)
  const int wc   = wave & 3;      // 0..3  (wave-col: 64-col slab)
  const int quad = lane >> 4;
  const int ml   = lane & 15;

  const int tcol  = blockIdx.x;
  const int trow  = blockIdx.y;
  const int batch = blockIdx.z;

  const u16* Ab = A + (size_t)batch * NDIM * EDIM + (size_t)trow * BM * EDIM;
  const u16* Bb = B + (size_t)batch * MDIM * EDIM + (size_t)tcol * BN * EDIM;

  // ---- staging addressing (pre-swizzled global source; linear LDS dest) ----
  const int r0 = tid >> 3;                     // 0..63 (j adds 64)
  const int cs = (tid & 7) ^ (r0 & 7);
  const u16* gA = Ab + (size_t)r0 * EDIM + cs * 8;
  const u16* gB = Bb + (size_t)r0 * EDIM + cs * 8;

#define STG(buf, ab, h, gptr, t) do {                                          \
    const u16* _g = (gptr) + (size_t)((h) * 128) * EDIM + (size_t)(t) * BK;    \
    async_cp16(_g,                   &sh[buf][ab][(h) * 8192 + wave * 512]);   \
    async_cp16(_g + (size_t)64 * EDIM,                                         \
               &sh[buf][ab][(h) * 8192 + 4096 + wave * 512]);                  \
  } while (0)

  // ---- ds_read fragment addressing (swizzled) ----
  const int aBase = (wr * 128 + ml) * 64;
  const int bBase = (wc * 64 + ml) * 64;
  const int kc0 = ((quad     ) ^ (ml & 7)) * 8;   // ks=0
  const int kc1 = ((quad + 4 ) ^ (ml & 7)) * 8;   // ks=1

  short8 ar[4][2], br0[2][2], br1[2][2];
  f32x4 acc[8][4] = {};

#define LDA(buf, mh) do {                                                      \
    _Pragma("unroll")                                                          \
    for (int q = 0; q < 4; ++q) {                                              \
      ar[q][0] = *(const short8*)&sh[buf][0][aBase + (mh)*4096 + q*1024 + kc0];\
      ar[q][1] = *(const short8*)&sh[buf][0][aBase + (mh)*4096 + q*1024 + kc1];\
    } } while (0)

#define LDB(dst, buf, nh) do {                                                 \
    _Pragma("unroll")                                                          \
    for (int n = 0; n < 2; ++n) {                                              \
      dst[n][0] = *(const short8*)&sh[buf][1][bBase + (nh)*2048 + n*1024 + kc0];\
      dst[n][1] = *(const short8*)&sh[buf][1][bBase + (nh)*2048 + n*1024 + kc1];\
    } } while (0)

#define MM(mh, nh, BSRC) do {                                                  \
    __builtin_amdgcn_s_setprio(1);                                             \
    _Pragma("unroll")                                                          \
    for (int q = 0; q < 4; ++q)                                                \
      _Pragma("unroll")                                                        \
      for (int n = 0; n < 2; ++n)                                              \
        _Pragma("unroll")                                                      \
        for (int ks = 0; ks < 2; ++ks)                                         \
          acc[(mh)*4 + q][(nh)*2 + n] = __builtin_amdgcn_mfma_f32_16x16x32_bf16(\
              ar[q][ks], BSRC[n][ks], acc[(mh)*4 + q][(nh)*2 + n], 0, 0, 0);   \
    __builtin_amdgcn_s_setprio(0);                                             \
  } while (0)

  // ---- prologue: buf0 <- tile0 (all), buf1.B <- tile1 ----
  STG(0, 0, 0, gA, 0);   // b0.Ah0
  STG(0, 0, 1, gA, 0);   // b0.Ah1
  STG(0, 1, 0, gB, 0);   // b0.Bh0
  STG(0, 1, 1, gB, 0);   // b0.Bh1
  STG(1, 1, 0, gB, 1);   // b1.Bh0
  STG(1, 1, 1, gB, 1);   // b1.Bh1
  WAITVM(4);             // oldest 8 loads (= all of buf0) landed
  BAR();

  // ---- main loop: 8 phases / iteration, tiles (2i, 2i+1); prefetch (2i+2, 2i+3)
#pragma unroll 1
  for (int i = 0; i < 7; ++i) {
    const int t1 = 2 * i + 1, p0 = 2 * i + 2, p1 = 2 * i + 3;
    // ph1: Q00 of t0 (buf0)
    LDA(0, 0); LDB(br0, 0, 0);
    STG(1, 0, 0, gA, t1);
    BAR(); MM(0, 0, br0); BAR();
    // ph2: Q01
    LDB(br1, 0, 1);
    STG(1, 0, 1, gA, t1);
    BAR(); MM(0, 1, br1); BAR();
    // ph3: Q11
    LDA(0, 1);
    STG(0, 1, 0, gB, p0);
    BAR(); MM(1, 1, br1); BAR();
    // ph4: Q10 (no ds_reads)
    STG(0, 1, 1, gB, p0);
    WAITVM(4);                       // b1.A + prev b1.B landed
    BAR(); MM(1, 0, br0); BAR();
    // ph5: Q00 of t1 (buf1)
    LDA(1, 0); LDB(br0, 1, 0);
    STG(0, 0, 0, gA, p0);
    BAR(); MM(0, 0, br0); BAR();
    // ph6: Q01
    LDB(br1, 1, 1);
    STG(0, 0, 1, gA, p0);
    BAR(); MM(0, 1, br1); BAR();
    // ph7: Q11
    LDA(1, 1);
    STG(1, 1, 0, gB, p1);
    BAR(); MM(1, 1, br1); BAR();
    // ph8: Q10
    STG(1, 1, 1, gB, p1);
    WAITVM(4);                       // buf0 (= tile p0) landed
    BAR(); MM(1, 0, br0); BAR();
  }

  // ---- epilogue: tiles 14 (buf0), 15 (buf1) ----
  {
    // ph1
    LDA(0, 0); LDB(br0, 0, 0);
    STG(1, 0, 0, gA, 15);
    BAR(); MM(0, 0, br0); BAR();
    // ph2
    LDB(br1, 0, 1);
    STG(1, 0, 1, gA, 15);
    BAR(); MM(0, 1, br1); BAR();
    // ph3
    LDA(0, 1);
    BAR(); MM(1, 1, br1); BAR();
    // ph4
    WAITVM(0);                       // drain all of tile 15
    BAR(); MM(1, 0, br0); BAR();
    // ph5
    LDA(1, 0); LDB(br0, 1, 0);
    BAR(); MM(0, 0, br0); BAR();
    // ph6
    LDB(br1, 1, 1);
    BAR(); MM(0, 1, br1); BAR();
    // ph7
    LDA(1, 1);
    BAR(); MM(1, 1, br1); BAR();
    // ph8 (no more LDS hazards)
    MM(1, 0, br0);
  }

  // ---- C write ----
  float* Cb = C + (size_t)batch * NDIM * MDIM
                + (size_t)(trow * BM + wr * 128 + quad * 4) * MDIM
                + (tcol * BN + wc * 64 + ml);
#pragma unroll
  for (int mi = 0; mi < 8; ++mi) {
#pragma unroll
    for (int ni = 0; ni < 4; ++ni) {
      float* cp = Cb + (size_t)(mi * 16) * MDIM + ni * 16;
#pragma unroll
      for (int r = 0; r < 4; ++r)
        cp[(size_t)r * MDIM] = acc[mi][ni][r];
    }
  }
#undef STG
#undef LDA
#undef LDB
#undef MM
}

// ---------------- fallback: fused fp32->bf16 staging (R0-verified) ----------------
static constexpr int FBM = 128;
static constexpr int FBN = 128;
static constexpr int FBK = 32;
static constexpr int FKIT = EDIM / FBK;
static constexpr int LSTR = 40;

typedef __attribute__((ext_vector_type(2))) unsigned int u32x2;

__device__ __forceinline__ unsigned pk(float lo, float hi) {
  return __builtin_amdgcn_perm(__float_as_uint(hi), __float_as_uint(lo), 0x07060302u);
}
__device__ __forceinline__ u32x4 pack8(f32x4 x, f32x4 y) {
  u32x4 r;
  r[0] = pk(x[0], x[1]); r[1] = pk(x[2], x[3]);
  r[2] = pk(y[0], y[1]); r[3] = pk(y[2], y[3]);
  return r;
}

__global__ __launch_bounds__(256, 3)
void bmm_bt_kernel(const float* __restrict__ A, const float* __restrict__ B,
                   float* __restrict__ C) {
  __shared__ u16 As[FBM * LSTR];
  __shared__ u16 Bs[FBN * LSTR];

  const int tid  = threadIdx.x;
  const int lane = tid & 63;
  const int wave = tid >> 6;
  const int quad = lane >> 4;
  const int ml   = lane & 15;
  const int wrow = (wave >> 1) * 64;
  const int wcol = (wave & 1) * 64;

  const int tcol  = blockIdx.x;
  const int trow  = blockIdx.y;
  const int batch = blockIdx.z;

  const float* Ab = A + (size_t)batch * NDIM * EDIM + (size_t)trow * FBM * EDIM;
  const float* Bb = B + (size_t)batch * MDIM * EDIM + (size_t)tcol * FBN * EDIM;
  float*       Cb = C + (size_t)batch * NDIM * MDIM;

  const int r0 = tid >> 2;
  const int p0 = (tid & 3) * 8;
  const int r1 = r0 + 64;

  const float* pA0 = Ab + (size_t)r0 * EDIM + p0;
  const float* pA1 = Ab + (size_t)r1 * EDIM + p0;
  const float* pB0 = Bb + (size_t)r0 * EDIM + p0;
  const float* pB1 = Bb + (size_t)r1 * EDIM + p0;

  u16* wA0 = &As[r0 * LSTR + p0];
  u16* wA1 = &As[r1 * LSTR + p0];
  u16* wB0 = &Bs[r0 * LSTR + p0];
  u16* wB1 = &Bs[r1 * LSTR + p0];

  f32x4 a0 = *(const f32x4*)(pA0);
  f32x4 a1 = *(const f32x4*)(pA0 + 4);
  f32x4 a2 = *(const f32x4*)(pA1);
  f32x4 a3 = *(const f32x4*)(pA1 + 4);
  f32x4 b0 = *(const f32x4*)(pB0);
  f32x4 b1 = *(const f32x4*)(pB0 + 4);
  f32x4 b2 = *(const f32x4*)(pB1);
  f32x4 b3 = *(const f32x4*)(pB1 + 4);

  f32x4 acc[4][4] = {};

  for (int kb = 0; kb < FKIT; ++kb) {
    __syncthreads();
    *(u32x4*)wA0 = pack8(a0, a1);
    *(u32x4*)wA1 = pack8(a2, a3);
    *(u32x4*)wB0 = pack8(b0, b1);
    *(u32x4*)wB1 = pack8(b2, b3);
    __syncthreads();

    if (kb + 1 < FKIT) {
      const int off = (kb + 1) * FBK;
      a0 = *(const f32x4*)(pA0 + off);
      a1 = *(const f32x4*)(pA0 + off + 4);
      a2 = *(const f32x4*)(pA1 + off);
      a3 = *(const f32x4*)(pA1 + off + 4);
      b0 = *(const f32x4*)(pB0 + off);
      b1 = *(const f32x4*)(pB0 + off + 4);
      b2 = *(const f32x4*)(pB1 + off);
      b3 = *(const f32x4*)(pB1 + off + 4);
    }

    short8 af[4], bfr[4];
#pragma unroll
    for (int i = 0; i < 4; ++i)
      af[i] = *(const short8*)&As[(wrow + i * 16 + ml) * LSTR + quad * 8];
#pragma unroll
    for (int i = 0; i < 4; ++i)
      bfr[i] = *(const short8*)&Bs[(wcol + i * 16 + ml) * LSTR + quad * 8];

#pragma unroll
    for (int mi = 0; mi < 4; ++mi)
#pragma unroll
      for (int ni = 0; ni < 4; ++ni)
        acc[mi][ni] = __builtin_amdgcn_mfma_f32_16x16x32_bf16(
            af[mi], bfr[ni], acc[mi][ni], 0, 0, 0);
  }

  const int crow = trow * FBM + wrow + quad * 4;
  const int ccol = tcol * FBN + wcol + ml;
#pragma unroll
  for (int mi = 0; mi < 4; ++mi) {
#pragma unroll
    for (int ni = 0; ni < 4; ++ni) {
      float* cp = Cb + (size_t)(crow + mi * 16) * MDIM + (ccol + ni * 16);
#pragma unroll
      for (int r = 0; r < 4; ++r)
        cp[(size_t)r * MDIM] = acc[mi][ni][r];
    }
  }
}

extern "C" void kernel_launch(void* const* d_in, const int* in_sizes, int n_in,
                              void* d_out, int out_size, void* d_ws, size_t ws_size,
                              hipStream_t stream) {
  const float* A = (const float*)d_in[0];
  const float* B = (const float*)d_in[1];
  float*       C = (float*)d_out;

  const size_t elems = (size_t)BATCH * NDIM * EDIM;      // per matrix
  const size_t need  = 2 * elems * sizeof(u16);          // 64 MiB

  if (ws_size >= need) {
    u16* Abf = (u16*)d_ws;
    u16* Bbf = Abf + elems;
    cvt_kernel<<<2048, 256, 0, stream>>>(A, B, Abf, Bbf);
    dim3 grid(MDIM / BN, NDIM / BM, BATCH);              // 8 x 8 x 8
    bmm_8ph_kernel<<<grid, dim3(512), 0, stream>>>(Abf, Bbf, C);
  } else {
    dim3 grid(MDIM / FBN, NDIM / FBM, BATCH);
    bmm_bt_kernel<<<grid, dim3(256), 0, stream>>>(A, B, C);
  }
}

// Round 9
// 291.273 us; speedup vs baseline: 1.1255x; 1.0170x over previous
//
#include <hip/hip_runtime.h>

typedef __attribute__((ext_vector_type(8))) short short8;
typedef __attribute__((ext_vector_type(4))) float f32x4;
typedef unsigned short u16;
typedef __attribute__((address_space(1))) void gvoid;
typedef __attribute__((address_space(3))) void lvoid;

static constexpr int BATCH = 8;
static constexpr int NDIM  = 2048;
static constexpr int MDIM  = 2048;
static constexpr int EDIM  = 1024;
static constexpr int BM    = 256;
static constexpr int BN    = 256;
static constexpr int BK    = 32;     // fp32 K-step (same LDS bytes as bf16 BK=64)

#define BAR() do { asm volatile("" ::: "memory"); \
                   __builtin_amdgcn_s_barrier(); \
                   asm volatile("" ::: "memory"); } while (0)
#define WAITVM(N) asm volatile("s_waitcnt vmcnt(" #N ")" ::: "memory")

__device__ __forceinline__ void async_cp16(const void* g, void* l) {
  __builtin_amdgcn_global_load_lds((gvoid*)g, (lvoid*)l, 16, 0, 0);
}

// fp32x8 -> bf16x8 fragment (RNE via v_cvt_pk_bf16_f32; element order verified
// by R3-R7 passes: lo16 = first operand).
__device__ __forceinline__ short8 cvt_frag(f32x4 a, f32x4 b) {
  union { unsigned u[4]; short8 s; } r;
  asm("v_cvt_pk_bf16_f32 %0, %1, %2" : "=v"(r.u[0]) : "v"(a[0]), "v"(a[1]));
  asm("v_cvt_pk_bf16_f32 %0, %1, %2" : "=v"(r.u[1]) : "v"(a[2]), "v"(a[3]));
  asm("v_cvt_pk_bf16_f32 %0, %1, %2" : "=v"(r.u[2]) : "v"(b[0]), "v"(b[1]));
  asm("v_cvt_pk_bf16_f32 %0, %1, %2" : "=v"(r.u[3]) : "v"(b[2]), "v"(b[3]));
  return r.s;
}

// Single-kernel fp32 GEMM: R1's verified 256x256 8-phase schedule, with fp32
// staged directly to LDS via global_load_lds (zero staging registers) and
// fragment conversion to bf16 in-register after ds_read. Eliminates the cvt
// kernel's 201 MB pass + one dispatch gap. BK=32 fp32 => identical LDS bytes,
// identical staging-instruction counts, identical vmcnt schedule as R1.
__global__ __launch_bounds__(512, 2)
void bmm_f32_kernel(const float* __restrict__ A, const float* __restrict__ B,
                    float* __restrict__ C) {
  // [buf][A=0/B=1][256 rows x 32 f32], chunk-swizzled:
  // LDS[r][16B-chunk c] = global chunk (r, c ^ (r&7)), c in 0..7.  128 KiB.
  __shared__ float sh[2][2][BM * BK];

  const int tid  = threadIdx.x;
  const int lane = tid & 63;
  const int wave = tid >> 6;      // 0..7
  const int wr   = wave >> 2;     // 0..1  (128-row slab)
  const int wc   = wave & 3;      // 0..3  (64-col slab)
  const int quad = lane >> 4;
  const int ml   = lane & 15;

  // XCD-bijective swizzle (R4/R5-verified): 512 blocks = 8 XCDs x 64;
  // XCD x owns batch x -> fp32 panel re-reads are XCD-local.
  const int flat  = (int)blockIdx.x + 8 * (int)blockIdx.y + 64 * (int)blockIdx.z;
  const int nf    = (flat & 7) * 64 + (flat >> 3);
  const int batch = nf >> 6;
  const int trow  = (nf >> 3) & 7;
  const int tcol  = nf & 7;

  const float* Ab = A + (size_t)batch * NDIM * EDIM + (size_t)trow * BM * EDIM;
  const float* Bb = B + (size_t)batch * MDIM * EDIM + (size_t)tcol * BN * EDIM;

  // ---- staging addressing (pre-swizzled global source; linear LDS dest) ----
  // half-tile = 128 rows x 32 f32 = 16 KB = 2 instructions x (512 lanes x 16B).
  // instr j: rows j*64 + (tid>>3), global 16B-chunk (tid&7) ^ (row&7).
  const int r0 = tid >> 3;                     // 0..63
  const int cs = (tid & 7) ^ (r0 & 7);
  const float* gA = Ab + (size_t)r0 * EDIM + cs * 4;
  const float* gB = Bb + (size_t)r0 * EDIM + cs * 4;

#define STG(buf, ab, h, gptr, t) do {                                          \
    const float* _g = (gptr) + (size_t)((h) * 128) * EDIM + (size_t)(t) * BK;  \
    async_cp16(_g,                    &sh[buf][ab][(h) * 4096 + wave * 256]);  \
    async_cp16(_g + (size_t)64 * EDIM,                                         \
               &sh[buf][ab][(h) * 4096 + 2048 + wave * 256]);                  \
  } while (0)

  // ---- ds_read fragment addressing (swizzled) ----
  // A-frag (q): row = wr*128 + mh*64 + q*16 + ml, global chunks quad*2,+1.
  // LDS chunk = g ^ (row&7); row&7 == ml&7 (all row offsets are mult of 8).
  const int aBase = (wr * 128 + ml) * 32;
  const int bBase = (wc * 64 + ml) * 32;
  const int kc0 = ((quad * 2    ) ^ (ml & 7)) * 4;
  const int kc1 = ((quad * 2 + 1) ^ (ml & 7)) * 4;

  short8 ar[4], br0[2], br1[2];
  f32x4 acc[8][4] = {};

#define LDA(buf, mh) do {                                                      \
    _Pragma("unroll")                                                          \
    for (int q = 0; q < 4; ++q) {                                              \
      f32x4 _va = *(const f32x4*)&sh[buf][0][aBase + (mh)*2048 + q*512 + kc0]; \
      f32x4 _vb = *(const f32x4*)&sh[buf][0][aBase + (mh)*2048 + q*512 + kc1]; \
      ar[q] = cvt_frag(_va, _vb);                                              \
    } } while (0)

#define LDB(dst, buf, nh) do {                                                 \
    _Pragma("unroll")                                                          \
    for (int n = 0; n < 2; ++n) {                                              \
      f32x4 _va = *(const f32x4*)&sh[buf][1][bBase + (nh)*1024 + n*512 + kc0]; \
      f32x4 _vb = *(const f32x4*)&sh[buf][1][bBase + (nh)*1024 + n*512 + kc1]; \
      dst[n] = cvt_frag(_va, _vb);                                             \
    } } while (0)

#define MM(mh, nh, BSRC) do {                                                  \
    __builtin_amdgcn_s_setprio(1);                                             \
    _Pragma("unroll")                                                          \
    for (int q = 0; q < 4; ++q)                                                \
      _Pragma("unroll")                                                        \
      for (int n = 0; n < 2; ++n)                                              \
        acc[(mh)*4 + q][(nh)*2 + n] = __builtin_amdgcn_mfma_f32_16x16x32_bf16( \
            ar[q], BSRC[n], acc[(mh)*4 + q][(nh)*2 + n], 0, 0, 0);             \
    __builtin_amdgcn_s_setprio(0);                                             \
  } while (0)

  // ---- prologue: buf0 <- tile0 (all), buf1.B <- tile1 ----
  STG(0, 0, 0, gA, 0);
  STG(0, 0, 1, gA, 0);
  STG(0, 1, 0, gB, 0);
  STG(0, 1, 1, gB, 0);
  STG(1, 1, 0, gB, 1);
  STG(1, 1, 1, gB, 1);
  WAITVM(4);             // oldest 8 loads (= all of buf0) landed
  BAR();

  // ---- main loop: 32 K-tiles, 8 phases per pair (2i, 2i+1); identical
  //      schedule/vmcnt discipline to the verified R1 kernel ----
#pragma unroll 1
  for (int i = 0; i < 15; ++i) {
    const int t1 = 2 * i + 1, p0 = 2 * i + 2, p1 = 2 * i + 3;
    // ph1: Q00 of t0 (buf0)
    LDA(0, 0); LDB(br0, 0, 0);
    STG(1, 0, 0, gA, t1);
    BAR(); MM(0, 0, br0); BAR();
    // ph2: Q01
    LDB(br1, 0, 1);
    STG(1, 0, 1, gA, t1);
    BAR(); MM(0, 1, br1); BAR();
    // ph3: Q11
    LDA(0, 1);
    STG(0, 1, 0, gB, p0);
    BAR(); MM(1, 1, br1); BAR();
    // ph4: Q10 (no ds_reads)
    STG(0, 1, 1, gB, p0);
    WAITVM(4);                       // b1.A landed
    BAR(); MM(1, 0, br0); BAR();
    // ph5: Q00 of t1 (buf1)
    LDA(1, 0); LDB(br0, 1, 0);
    STG(0, 0, 0, gA, p0);
    BAR(); MM(0, 0, br0); BAR();
    // ph6: Q01
    LDB(br1, 1, 1);
    STG(0, 0, 1, gA, p0);
    BAR(); MM(0, 1, br1); BAR();
    // ph7: Q11
    LDA(1, 1);
    STG(1, 1, 0, gB, p1);
    BAR(); MM(1, 1, br1); BAR();
    // ph8: Q10
    STG(1, 1, 1, gB, p1);
    WAITVM(4);                       // buf0 (= tile p0) landed
    BAR(); MM(1, 0, br0); BAR();
  }

  // ---- epilogue: tiles 30 (buf0), 31 (buf1) ----
  {
    // ph1
    LDA(0, 0); LDB(br0, 0, 0);
    STG(1, 0, 0, gA, 31);
    BAR(); MM(0, 0, br0); BAR();
    // ph2
    LDB(br1, 0, 1);
    STG(1, 0, 1, gA, 31);
    BAR(); MM(0, 1, br1); BAR();
    // ph3
    LDA(0, 1);
    BAR(); MM(1, 1, br1); BAR();
    // ph4
    WAITVM(0);                       // drain all of tile 31
    BAR(); MM(1, 0, br0); BAR();
    // ph5
    LDA(1, 0); LDB(br0, 1, 0);
    BAR(); MM(0, 0, br0); BAR();
    // ph6
    LDB(br1, 1, 1);
    BAR(); MM(0, 1, br1); BAR();
    // ph7
    LDA(1, 1);
    BAR(); MM(1, 1, br1); BAR();
    // ph8 (no more LDS hazards)
    MM(1, 0, br0);
  }

  // ---- C write (verified mapping) ----
  float* Cb = C + (size_t)batch * NDIM * MDIM
                + (size_t)(trow * BM + wr * 128 + quad * 4) * MDIM
                + (tcol * BN + wc * 64 + ml);
#pragma unroll
  for (int mi = 0; mi < 8; ++mi) {
#pragma unroll
    for (int ni = 0; ni < 4; ++ni) {
      float* cp = Cb + (size_t)(mi * 16) * MDIM + ni * 16;
#pragma unroll
      for (int r = 0; r < 4; ++r)
        cp[(size_t)r * MDIM] = acc[mi][ni][r];
    }
  }
#undef STG
#undef LDA
#undef LDB
#undef MM
}

extern "C" void kernel_launch(void* const* d_in, const int* in_sizes, int n_in,
                              void* d_out, int out_size, void* d_ws, size_t ws_size,
                              hipStream_t stream) {
  const float* A = (const float*)d_in[0];
  const float* B = (const float*)d_in[1];
  float*       C = (float*)d_out;
  (void)d_ws; (void)ws_size;   // workspace-free single-kernel path

  dim3 grid(MDIM / BN, NDIM / BM, BATCH);   // 8 x 8 x 8 = 512
  bmm_f32_kernel<<<grid, dim3(512), 0, stream>>>(A, B, C);
}